// Round 5
// baseline (353.133 us; speedup 1.0000x reference)
//
#include <hip/hip_runtime.h>
#include <math.h>

// Problem constants
#define B_  16
#define H_  480
#define W_  640
#define HW_ (H_*W_)
#define C_  256
#define HC_ 60
#define WC_ 80
#define K_  400
#define NCAND 8192

// counters padded: count[b*COUNT_STRIDE] (unsigned), 256B apart.
// d_ws is poisoned 0xAA before every call, so counters start at 0xAAAAAAAA;
// nms atomicAdds on top of that base and readers subtract it.
// sample/norm ticket lives at count[b*COUNT_STRIDE + 32] (separate cacheline).
#define COUNT_STRIDE 64
#define POISON_U32 0xAAAAAAAAu

// out layout (floats): kpts[16*400*2] | scores[16*400] | sampled[16*256*400] | heatmap[16*480*640]
#define OFF_KPTS    0
#define OFF_SCORES  (16*400*2)
#define OFF_SAMPLED (OFF_SCORES + 16*400)
#define OFF_HEAT    (OFF_SAMPLED + 16*256*400)

// ---------------------------------------------------------------------------
// NMS (7x7 window max, SAME padding -inf) + border mask + compaction.
// 64x32 tile, 8 outputs/thread, float4 LDS staging; passthrough copy writes
// CORE quads only (each pixel written exactly once grid-wide — no duplicate
// halo writes, no cross-XCD same-line write churn).
// block (64,4). grid (10, 15, 16) = 2400 blocks.
#define TW 64
#define TH 32
#define TSTR 72   // tile row stride in floats; row covers gx in [tx0-4, tx0+67]
__global__ __launch_bounds__(256) void nms_kernel(
    const float* __restrict__ heat, float* __restrict__ out_heat,
    unsigned long long* __restrict__ cand, unsigned* __restrict__ count)
{
    const int b   = blockIdx.z;
    const int tx0 = blockIdx.x * TW;
    const int ty0 = blockIdx.y * TH;
    const float* hb = heat + (size_t)b * HW_;
    float*       oh = out_heat + (size_t)b * HW_;

    __shared__ __attribute__((aligned(16))) float tile[(TH+6)*TSTR]; // 38x72
    __shared__ float hmax[(TH+6)*TW];                                // 38x64
    __shared__ int   wbase[4];
    __shared__ int   blockbase;

    const int tx  = threadIdx.x;   // 0..63 (lane)
    const int wv  = threadIdx.y;   // 0..3  (wave)
    const int tid = wv*64 + tx;

    // ---- stage 38 x 72 window as float4; passthrough core quads only ----
    // core: r in [3,35), c4 in [1,17) -> gy in [ty0,ty0+32), gxb in [tx0,tx0+64)
    const bool interior = (tx0 >= 4) && (tx0 + 68 <= W_) &&
                          (ty0 >= 3) && (ty0 + 35 <= H_);
    if (interior) {
        for (int i = tid; i < 38*18; i += 256) {
            int r  = i / 18, c4 = i - r*18;
            int gy  = ty0 + r - 3;
            int gxb = tx0 + c4*4 - 4;
            float4 f = *(const float4*)(hb + gy*W_ + gxb);
            *(float4*)&tile[r*TSTR + c4*4] = f;
            if (r >= 3 && r < 35 && c4 >= 1 && c4 < 17)
                *(float4*)(oh + gy*W_ + gxb) = f;   // passthrough (core only)
        }
    } else {
        for (int i = tid; i < 38*18; i += 256) {
            int r  = i / 18, c4 = i - r*18;
            int gy  = ty0 + r - 3;
            int gxb = tx0 + c4*4 - 4;
            float4 f;
            if (gy >= 0 && gy < H_ && gxb >= 0 && gxb + 3 < W_) {
                f = *(const float4*)(hb + gy*W_ + gxb);
                if (r >= 3 && r < 35 && c4 >= 1 && c4 < 17)
                    *(float4*)(oh + gy*W_ + gxb) = f;   // passthrough (core only)
            } else {
                f = make_float4(-INFINITY, -INFINITY, -INFINITY, -INFINITY);
            }
            *(float4*)&tile[r*TSTR + c4*4] = f;
        }
    }
    __syncthreads();

    // ---- horizontal 7-max: 38 rows x 8 segments of 8 outputs ----
    for (int s = tid; s < 38*8; s += 256) {
        int r = s >> 3, c0 = (s & 7) << 3;
        const float* trow = &tile[r*TSTR + c0];
        float4 qa = *(const float4*)(trow);
        float4 qb = *(const float4*)(trow + 4);
        float4 qc = *(const float4*)(trow + 8);
        float4 qd = *(const float4*)(trow + 12);
        float w[14] = {qa.y,qa.z,qa.w, qb.x,qb.y,qb.z,qb.w,
                       qc.x,qc.y,qc.z,qc.w, qd.x,qd.y,qd.z};
        float suf[7]; suf[6] = w[6];
        #pragma unroll
        for (int j = 5; j >= 0; --j) suf[j] = fmaxf(w[j], suf[j+1]);
        float pre[7]; pre[0] = w[7];
        #pragma unroll
        for (int j = 1; j < 7; ++j) pre[j] = fmaxf(pre[j-1], w[7+j]);
        float m[8];
        m[0] = suf[0];
        #pragma unroll
        for (int j = 1; j < 7; ++j) m[j] = fmaxf(suf[j], pre[j-1]);
        m[7] = pre[6];
        *(float4*)&hmax[r*TW + c0]     = make_float4(m[0],m[1],m[2],m[3]);
        *(float4*)&hmax[r*TW + c0 + 4] = make_float4(m[4],m[5],m[6],m[7]);
    }
    __syncthreads();

    // ---- vertical 7-max in registers: thread owns rows ry0..ry0+7, col tx ----
    const int ry0 = wv * 8;
    float h[14];
    #pragma unroll
    for (int i = 0; i < 14; ++i) h[i] = hmax[(ry0+i)*TW + tx];
    float suf[7]; suf[6] = h[6];
    #pragma unroll
    for (int j = 5; j >= 0; --j) suf[j] = fmaxf(h[j], suf[j+1]);
    float pre[7]; pre[0] = h[7];
    #pragma unroll
    for (int j = 1; j < 7; ++j) pre[j] = fmaxf(pre[j-1], h[7+j]);
    float vm[8];
    vm[0] = suf[0];
    #pragma unroll
    for (int j = 1; j < 7; ++j) vm[j] = fmaxf(suf[j], pre[j-1]);
    vm[7] = pre[6];

    const int gx = tx0 + tx;
    float v[8];
    bool  flag[8];
    #pragma unroll
    for (int j = 0; j < 8; ++j) {
        int ry = ry0 + j;
        int gy = ty0 + ry;
        float val = tile[(ry+3)*TSTR + tx + 4];
        v[j] = val;
        flag[j] = (val >= vm[j]) && (val > 0.0f) &&
                  (gx >= 4) && (gx < W_-4) && (gy >= 4) && (gy < H_-4);
    }

    unsigned long long masks[8];
    #pragma unroll
    for (int j = 0; j < 8; ++j) masks[j] = __ballot(flag[j]);

    if (tx == 0) {
        int t = 0;
        #pragma unroll
        for (int j = 0; j < 8; ++j) t += __popcll(masks[j]);
        wbase[wv] = t;
    }
    __syncthreads();
    if (tid == 0) {
        int acc = 0;
        #pragma unroll
        for (int w = 0; w < 4; ++w) { int t = wbase[w]; wbase[w] = acc; acc += t; }
        blockbase = (acc > 0)
            ? (int)(atomicAdd(&count[b * COUNT_STRIDE], (unsigned)acc) - POISON_U32)
            : 0;
    }
    __syncthreads();

    const unsigned long long lt = (tx == 63) ? 0x7FFFFFFFFFFFFFFFULL
                                             : ((1ULL << tx) - 1ULL);
    int prior = 0;
    const int base = blockbase + wbase[wv];
    #pragma unroll
    for (int j = 0; j < 8; ++j) {
        if (flag[j]) {
            int pos = base + prior + __popcll(masks[j] & lt);
            if (pos < NCAND) {
                unsigned idx = (unsigned)((ty0+ry0+j)*W_ + gx);
                unsigned vb  = __float_as_uint(v[j]);   // v>0: uint order == float order
                cand[(size_t)b*NCAND + pos] =
                    ((unsigned long long)vb << 32) | (unsigned long long)(~idx);
            }
        }
        prior += __popcll(masks[j]);
    }
}

// ---------------------------------------------------------------------------
// Wave-aggregated LDS histogram add (kept from round 4 — passed).
__device__ inline void hist_wave_add(int* hist, unsigned g, bool val, int lane) {
    unsigned long long vm = __ballot(val);
    if (vm == 0ULL) return;
    int lead = __ffsll(vm) - 1;
    unsigned g0 = __shfl(g, lead);
    unsigned long long same = __ballot(val && (g == g0));
    if (val) {
        if (g == g0) {
            if (lane == lead) atomicAdd(&hist[g0], (int)__popcll(same));
        } else {
            atomicAdd(&hist[g], 1);
        }
    }
}

// ---------------------------------------------------------------------------
// Top-400 per batch: keys staged in LDS; 3-level radix select (11/11/10 bits)
// with wave-shuffle suffix scans; collect keys >= exact 400th value T;
// counting-rank -> direct ordered write. key = value<<32 | ~idx.
__global__ __launch_bounds__(1024) void topk_kernel(
    const unsigned long long* __restrict__ cand, const unsigned* __restrict__ count,
    float* __restrict__ kpts, float* __restrict__ scores)
{
    const int b = blockIdx.x;
    const int tid = threadIdx.x;
    const int lane = tid & 63;
    const int wv   = tid >> 6;      // 16 waves
    int cnt = (int)(count[b * COUNT_STRIDE] - POISON_U32);
    if (cnt > NCAND) cnt = NCAND;
    if (cnt < 0) cnt = 0;
    const unsigned long long* cb = cand + (size_t)b * NCAND;

    __shared__ unsigned long long keys[NCAND];   // 64 KB
    __shared__ int hist[2048];                   // 8 KB
    __shared__ int ssLDS[1024];                  // 4 KB
    __shared__ unsigned long long sel[1024];     // 8 KB
    __shared__ int wsuf[17];
    __shared__ int sh_need, sh_prefix, sh_p, sh_selcnt;

    if (tid == 0) { sh_need = K_; sh_prefix = 0; sh_selcnt = 0; }
    hist[tid] = 0; hist[tid + 1024] = 0;
    __syncthreads();

    // stage keys into LDS, fused with level-0 histogram (bits 31..21).
    for (int i0 = 0; i0 < cnt; i0 += 1024) {
        const int i = i0 + tid;
        const bool val = (i < cnt);
        unsigned long long k = 0ULL;
        if (val) { k = cb[i]; keys[i] = k; }
        unsigned g = (unsigned)(k >> 32) >> 21;
        hist_wave_add(hist, g, val, lane);
    }
    __syncthreads();

    for (int lvl = 0; lvl < 3; ++lvl) {
        // suffix scan of 1024 pair-sums via wave shuffles
        int s = hist[2*tid] + hist[2*tid + 1];
        #pragma unroll
        for (int off = 1; off < 64; off <<= 1) {
            int t = __shfl_down(s, off);
            if (lane + off < 64) s += t;
        }
        if (lane == 0) wsuf[wv] = s;
        __syncthreads();
        if (tid < 16) {
            int t2 = wsuf[tid];
            #pragma unroll
            for (int off = 1; off < 16; off <<= 1) {
                int u = __shfl_down(t2, off);
                if (tid + off < 16) t2 += u;
            }
            wsuf[tid] = t2;
            if (tid == 0) wsuf[16] = 0;
        }
        __syncthreads();
        int ss = s + wsuf[wv + 1];
        ssLDS[tid] = ss;
        __syncthreads();

        const int need = sh_need;
        int sp  = ssLDS[tid];
        int spn = (tid < 1023) ? ssLDS[tid + 1] : 0;
        if (sp >= need && spn < need) sh_p = tid;
        __syncthreads();
        const int shift = (lvl == 0) ? 21 : ((lvl == 1) ? 10 : 0);
        if (tid == 0) {
            int p   = sh_p;
            int abv = (p < 1023) ? ssLDS[p + 1] : 0;
            int hi  = hist[2*p + 1];
            int g, above;
            if (abv + hi >= need) { g = 2*p + 1; above = abv; }
            else                  { g = 2*p;     above = abv + hi; }
            sh_need   = need - above;
            sh_prefix = sh_prefix | (g << shift);
        }
        __syncthreads();
        if (lvl == 2) break;

        // next-level histogram from LDS keys (wave-aggregated adds)
        hist[tid] = 0; hist[tid + 1024] = 0;
        __syncthreads();
        const unsigned nshift = (lvl == 0) ? 10u : 0u;
        const unsigned npmask = (lvl == 0) ? 0xFFE00000u : 0xFFFFFC00u;
        const unsigned prefix = (unsigned)sh_prefix;
        for (int i0 = 0; i0 < cnt; i0 += 1024) {
            const int i = i0 + tid;
            const bool val = (i < cnt);
            unsigned v = val ? (unsigned)(keys[i] >> 32) : 0u;
            bool pass = val && ((v & npmask) == prefix);
            unsigned g = (v >> nshift) & 0x7FF;
            hist_wave_add(hist, g, pass, lane);
        }
        __syncthreads();
    }

    // collect all keys with value >= T (exact 400th-largest value).
    const unsigned T = (unsigned)sh_prefix;
    const unsigned long long ltm = (1ULL << lane) - 1ULL;
    for (int i0 = 0; i0 < cnt; i0 += 1024) {
        const int i = i0 + tid;
        const bool val = (i < cnt);
        unsigned long long k = val ? keys[i] : 0ULL;
        bool pick = val && ((unsigned)(k >> 32) >= T);
        unsigned long long m = __ballot(pick);
        if (pick) {
            int lead = __ffsll(m) - 1;
            int basepos;
            if (lane == lead) basepos = atomicAdd(&sh_selcnt, (int)__popcll(m));
            basepos = __shfl(basepos, lead);
            int pos = basepos + (int)__popcll(m & ltm);
            if (pos < 1024) sel[pos] = k;
        }
    }
    __syncthreads();
    int sc = sh_selcnt; if (sc > 1024) sc = 1024;

    // counting rank (keys unique): rank = #{j: sel[j] > mine}
    unsigned long long mykey = (tid < sc) ? sel[tid] : 0ULL;
    int rank = 0;
    for (int j = 0; j < sc; ++j) rank += (sel[j] > mykey) ? 1 : 0;

    if (tid < sc && rank < K_) {
        unsigned vb  = (unsigned)(mykey >> 32);
        unsigned idx = ~((unsigned)mykey);
        int y = (int)(idx / W_), x = (int)(idx % W_);
        kpts[b*(K_*2) + rank*2 + 0] = (float)x + 0.5f;
        kpts[b*(K_*2) + rank*2 + 1] = (float)y + 0.5f;
        scores[b*K_ + rank] = __uint_as_float(vb);
    }
}

// ---------------------------------------------------------------------------
// bilinear descriptor sampling + fused per-batch L2 norm.
// One block per (channel, batch), 512 threads; whole 60x80 plane staged in
// LDS. After writing its channel, each block tickets count[b*64+32]; the LAST
// of the 256 blocks of batch b (release/acquire __threadfence pair — the
// round-3-proven pattern) L2-normalizes the whole batch in place:
// 25 k-groups of 16 keypoints over 2 virtual 256-thread groups.
__global__ __launch_bounds__(512) void sample_norm_kernel(
    const float* __restrict__ desc, const float* __restrict__ kpts,
    float* __restrict__ sampled, unsigned* __restrict__ count)
{
    const int c = blockIdx.x;   // 0..255
    const int b = blockIdx.y;   // 0..15
    const int tid = threadIdx.x;
    __shared__ float plane[HC_*WC_];   // 4800 floats = 19.2 KB
    __shared__ float wpart[2][4][16];
    __shared__ int lastflag;

    // preload this thread's keypoint (clamped index; only tid<K_ writes out)
    const int kk = (tid < K_) ? tid : (K_-1);
    const float x = kpts[b*(K_*2) + 2*kk + 0];
    const float y = kpts[b*(K_*2) + 2*kk + 1];

    const float4* p4 = (const float4*)(desc + ((size_t)b*C_ + c) * (HC_*WC_));
    for (int i = tid; i < HC_*WC_/4; i += 512)
        ((float4*)plane)[i] = p4[i];
    __syncthreads();

    if (tid < K_) {
        float gx = (x - 3.5f) * (79.0f / 635.5f);
        float gy = (y - 3.5f) * (59.0f / 475.5f);
        float x0f = floorf(gx), y0f = floorf(gy);
        float wx = gx - x0f,   wy = gy - y0f;
        int x0 = min(max((int)x0f, 0), WC_-1);
        int x1 = min(x0 + 1, WC_-1);
        int y0 = min(max((int)y0f, 0), HC_-1);
        int y1 = min(y0 + 1, HC_-1);
        float d00 = plane[y0*WC_ + x0], d01 = plane[y0*WC_ + x1];
        float d10 = plane[y1*WC_ + x0], d11 = plane[y1*WC_ + x1];
        float v = d00*(1.0f-wx)*(1.0f-wy) + d01*wx*(1.0f-wy)
                + d10*(1.0f-wx)*wy        + d11*wx*wy;
        sampled[(size_t)b*(C_*K_) + c*K_ + tid] = v;   // unnormalized
    }

    // ---- last-block ticket (no spin, no residency assumption) ----
    __syncthreads();                        // all stores issued (vmcnt drained)
    if (tid == 0) {
        __threadfence();                    // release: write back this XCD L2
        unsigned old = atomicAdd(&count[b * COUNT_STRIDE + 32], 1u);
        lastflag = (old == POISON_U32 + (C_ - 1)) ? 1 : 0;
    }
    __syncthreads();
    if (!lastflag) return;                  // 255 of 256 blocks exit here
    if (tid == 0) __threadfence();          // acquire: invalidate stale lines
    __syncthreads();

    // ---- L2 norm for batch b: same arithmetic/order as proven norm_fused ----
    const int s2   = tid >> 8;              // virtual 256-group 0..1
    const int t2   = tid & 255;
    const int lane = tid & 63;
    const int wv2  = (tid >> 6) & 3;        // wave within virtual group
    float* base = sampled + (size_t)b*(C_*K_);

    for (int it = 0; it < 13; ++it) {
        const int kg = s2 + 2*it;           // k-group 0..25 (25 invalid)
        const bool act = (kg < 25);
        const int k  = kg*16 + (t2 & 15);
        const int cs = t2 >> 4;             // 0..15
        float vv[16];
        float acc = 0.0f;
        if (act) {
            #pragma unroll
            for (int i = 0; i < 16; ++i) {
                float t = base[(cs + 16*i)*K_ + k];
                vv[i] = t;
                acc += t*t;
            }
        }
        acc += __shfl_xor(acc, 16);
        acc += __shfl_xor(acc, 32);
        if (lane < 16) wpart[s2][wv2][lane] = acc;
        __syncthreads();
        if (act) {
            const int kk2 = t2 & 15;
            float ssum = wpart[s2][0][kk2] + wpart[s2][1][kk2]
                       + wpart[s2][2][kk2] + wpart[s2][3][kk2];
            float inv = rsqrtf(ssum + 1e-12f);
            #pragma unroll
            for (int i = 0; i < 16; ++i)
                base[(cs + 16*i)*K_ + k] = vv[i] * inv;
        }
        __syncthreads();
    }
}

// ---------------------------------------------------------------------------
extern "C" void kernel_launch(void* const* d_in, const int* in_sizes, int n_in,
                              void* d_out, int out_size, void* d_ws, size_t ws_size,
                              hipStream_t stream) {
    const float* heat = (const float*)d_in[0];   // (16,1,480,640)
    const float* desc = (const float*)d_in[1];   // (16,256,60,80)
    float* out      = (float*)d_out;
    float* kpts     = out + OFF_KPTS;
    float* scores   = out + OFF_SCORES;
    float* sampled  = out + OFF_SAMPLED;
    float* out_heat = out + OFF_HEAT;

    unsigned* count = (unsigned*)d_ws;            // 16 counters + tickets, poison-based
    unsigned long long* cand =
        (unsigned long long*)((char*)d_ws + 16*COUNT_STRIDE*sizeof(unsigned)); // 1 MB

    nms_kernel<<<dim3(W_/TW, H_/TH, B_), dim3(64, 4), 0, stream>>>(
        heat, out_heat, cand, count);
    topk_kernel<<<B_, 1024, 0, stream>>>(cand, count, kpts, scores);
    sample_norm_kernel<<<dim3(C_, B_), 512, 0, stream>>>(desc, kpts, sampled, count);
}

// Round 6
// 173.451 us; speedup vs baseline: 2.0359x; 2.0359x over previous
//
#include <hip/hip_runtime.h>
#include <math.h>

// Problem constants
#define B_  16
#define H_  480
#define W_  640
#define HW_ (H_*W_)
#define C_  256
#define HC_ 60
#define WC_ 80
#define K_  400
#define NCAND 8192

// counters padded: count[b*COUNT_STRIDE] (unsigned), 256B apart.
// d_ws is poisoned 0xAA before every call, so counters start at 0xAAAAAAAA;
// nms atomicAdds on top of that base and readers subtract it.
#define COUNT_STRIDE 64
#define POISON_U32 0xAAAAAAAAu

// out layout (floats): kpts[16*400*2] | scores[16*400] | sampled[16*256*400] | heatmap[16*480*640]
#define OFF_KPTS    0
#define OFF_SCORES  (16*400*2)
#define OFF_SAMPLED (OFF_SCORES + 16*400)
#define OFF_HEAT    (OFF_SAMPLED + 16*256*400)

// ---------------------------------------------------------------------------
// NMS (7x7 window max, SAME padding -inf) + border mask + compaction.
// 64x32 tile, 8 outputs/thread, float4 LDS staging; passthrough copy writes
// CORE quads only (each pixel written exactly once grid-wide).
// block (64,4). grid (10, 15, 16) = 2400 blocks.
#define TW 64
#define TH 32
#define TSTR 72   // tile row stride in floats; row covers gx in [tx0-4, tx0+67]
__global__ __launch_bounds__(256) void nms_kernel(
    const float* __restrict__ heat, float* __restrict__ out_heat,
    unsigned long long* __restrict__ cand, unsigned* __restrict__ count)
{
    const int b   = blockIdx.z;
    const int tx0 = blockIdx.x * TW;
    const int ty0 = blockIdx.y * TH;
    const float* hb = heat + (size_t)b * HW_;
    float*       oh = out_heat + (size_t)b * HW_;

    __shared__ __attribute__((aligned(16))) float tile[(TH+6)*TSTR]; // 38x72
    __shared__ float hmax[(TH+6)*TW];                                // 38x64
    __shared__ int   wbase[4];
    __shared__ int   blockbase;

    const int tx  = threadIdx.x;   // 0..63 (lane)
    const int wv  = threadIdx.y;   // 0..3  (wave)
    const int tid = wv*64 + tx;

    // ---- stage 38 x 72 window as float4; passthrough core quads only ----
    // core: r in [3,35), c4 in [1,17) -> gy in [ty0,ty0+32), gxb in [tx0,tx0+64)
    const bool interior = (tx0 >= 4) && (tx0 + 68 <= W_) &&
                          (ty0 >= 3) && (ty0 + 35 <= H_);
    if (interior) {
        for (int i = tid; i < 38*18; i += 256) {
            int r  = i / 18, c4 = i - r*18;
            int gy  = ty0 + r - 3;
            int gxb = tx0 + c4*4 - 4;
            float4 f = *(const float4*)(hb + gy*W_ + gxb);
            *(float4*)&tile[r*TSTR + c4*4] = f;
            if (r >= 3 && r < 35 && c4 >= 1 && c4 < 17)
                *(float4*)(oh + gy*W_ + gxb) = f;   // passthrough (core only)
        }
    } else {
        for (int i = tid; i < 38*18; i += 256) {
            int r  = i / 18, c4 = i - r*18;
            int gy  = ty0 + r - 3;
            int gxb = tx0 + c4*4 - 4;
            float4 f;
            if (gy >= 0 && gy < H_ && gxb >= 0 && gxb + 3 < W_) {
                f = *(const float4*)(hb + gy*W_ + gxb);
                if (r >= 3 && r < 35 && c4 >= 1 && c4 < 17)
                    *(float4*)(oh + gy*W_ + gxb) = f;   // passthrough (core only)
            } else {
                f = make_float4(-INFINITY, -INFINITY, -INFINITY, -INFINITY);
            }
            *(float4*)&tile[r*TSTR + c4*4] = f;
        }
    }
    __syncthreads();

    // ---- horizontal 7-max: 38 rows x 8 segments of 8 outputs ----
    for (int s = tid; s < 38*8; s += 256) {
        int r = s >> 3, c0 = (s & 7) << 3;
        const float* trow = &tile[r*TSTR + c0];
        float4 qa = *(const float4*)(trow);
        float4 qb = *(const float4*)(trow + 4);
        float4 qc = *(const float4*)(trow + 8);
        float4 qd = *(const float4*)(trow + 12);
        float w[14] = {qa.y,qa.z,qa.w, qb.x,qb.y,qb.z,qb.w,
                       qc.x,qc.y,qc.z,qc.w, qd.x,qd.y,qd.z};
        float suf[7]; suf[6] = w[6];
        #pragma unroll
        for (int j = 5; j >= 0; --j) suf[j] = fmaxf(w[j], suf[j+1]);
        float pre[7]; pre[0] = w[7];
        #pragma unroll
        for (int j = 1; j < 7; ++j) pre[j] = fmaxf(pre[j-1], w[7+j]);
        float m[8];
        m[0] = suf[0];
        #pragma unroll
        for (int j = 1; j < 7; ++j) m[j] = fmaxf(suf[j], pre[j-1]);
        m[7] = pre[6];
        *(float4*)&hmax[r*TW + c0]     = make_float4(m[0],m[1],m[2],m[3]);
        *(float4*)&hmax[r*TW + c0 + 4] = make_float4(m[4],m[5],m[6],m[7]);
    }
    __syncthreads();

    // ---- vertical 7-max in registers: thread owns rows ry0..ry0+7, col tx ----
    const int ry0 = wv * 8;
    float h[14];
    #pragma unroll
    for (int i = 0; i < 14; ++i) h[i] = hmax[(ry0+i)*TW + tx];
    float suf[7]; suf[6] = h[6];
    #pragma unroll
    for (int j = 5; j >= 0; --j) suf[j] = fmaxf(h[j], suf[j+1]);
    float pre[7]; pre[0] = h[7];
    #pragma unroll
    for (int j = 1; j < 7; ++j) pre[j] = fmaxf(pre[j-1], h[7+j]);
    float vm[8];
    vm[0] = suf[0];
    #pragma unroll
    for (int j = 1; j < 7; ++j) vm[j] = fmaxf(suf[j], pre[j-1]);
    vm[7] = pre[6];

    const int gx = tx0 + tx;
    float v[8];
    bool  flag[8];
    #pragma unroll
    for (int j = 0; j < 8; ++j) {
        int ry = ry0 + j;
        int gy = ty0 + ry;
        float val = tile[(ry+3)*TSTR + tx + 4];
        v[j] = val;
        flag[j] = (val >= vm[j]) && (val > 0.0f) &&
                  (gx >= 4) && (gx < W_-4) && (gy >= 4) && (gy < H_-4);
    }

    unsigned long long masks[8];
    #pragma unroll
    for (int j = 0; j < 8; ++j) masks[j] = __ballot(flag[j]);

    if (tx == 0) {
        int t = 0;
        #pragma unroll
        for (int j = 0; j < 8; ++j) t += __popcll(masks[j]);
        wbase[wv] = t;
    }
    __syncthreads();
    if (tid == 0) {
        int acc = 0;
        #pragma unroll
        for (int w = 0; w < 4; ++w) { int t = wbase[w]; wbase[w] = acc; acc += t; }
        blockbase = (acc > 0)
            ? (int)(atomicAdd(&count[b * COUNT_STRIDE], (unsigned)acc) - POISON_U32)
            : 0;
    }
    __syncthreads();

    const unsigned long long lt = (tx == 63) ? 0x7FFFFFFFFFFFFFFFULL
                                             : ((1ULL << tx) - 1ULL);
    int prior = 0;
    const int base = blockbase + wbase[wv];
    #pragma unroll
    for (int j = 0; j < 8; ++j) {
        if (flag[j]) {
            int pos = base + prior + __popcll(masks[j] & lt);
            if (pos < NCAND) {
                unsigned idx = (unsigned)((ty0+ry0+j)*W_ + gx);
                unsigned vb  = __float_as_uint(v[j]);   // v>0: uint order == float order
                cand[(size_t)b*NCAND + pos] =
                    ((unsigned long long)vb << 32) | (unsigned long long)(~idx);
            }
        }
        prior += __popcll(masks[j]);
    }
}

// ---------------------------------------------------------------------------
// Wave-aggregated LDS histogram add (round-4 proven).
__device__ inline void hist_wave_add(int* hist, unsigned g, bool val, int lane) {
    unsigned long long vm = __ballot(val);
    if (vm == 0ULL) return;
    int lead = __ffsll(vm) - 1;
    unsigned g0 = __shfl(g, lead);
    unsigned long long same = __ballot(val && (g == g0));
    if (val) {
        if (g == g0) {
            if (lane == lead) atomicAdd(&hist[g0], (int)__popcll(same));
        } else {
            atomicAdd(&hist[g], 1);
        }
    }
}

// ---------------------------------------------------------------------------
// Top-400 per batch: keys staged in LDS; 3-level radix select (11/11/10 bits)
// with wave-shuffle suffix scans; collect keys >= exact 400th value T;
// counting-rank -> direct ordered write. key = value<<32 | ~idx.
__global__ __launch_bounds__(1024) void topk_kernel(
    const unsigned long long* __restrict__ cand, const unsigned* __restrict__ count,
    float* __restrict__ kpts, float* __restrict__ scores)
{
    const int b = blockIdx.x;
    const int tid = threadIdx.x;
    const int lane = tid & 63;
    const int wv   = tid >> 6;      // 16 waves
    int cnt = (int)(count[b * COUNT_STRIDE] - POISON_U32);
    if (cnt > NCAND) cnt = NCAND;
    if (cnt < 0) cnt = 0;
    const unsigned long long* cb = cand + (size_t)b * NCAND;

    __shared__ unsigned long long keys[NCAND];   // 64 KB
    __shared__ int hist[2048];                   // 8 KB
    __shared__ int ssLDS[1024];                  // 4 KB
    __shared__ unsigned long long sel[1024];     // 8 KB
    __shared__ int wsuf[17];
    __shared__ int sh_need, sh_prefix, sh_p, sh_selcnt;

    if (tid == 0) { sh_need = K_; sh_prefix = 0; sh_selcnt = 0; }
    hist[tid] = 0; hist[tid + 1024] = 0;
    __syncthreads();

    // stage keys into LDS, fused with level-0 histogram (bits 31..21).
    for (int i0 = 0; i0 < cnt; i0 += 1024) {
        const int i = i0 + tid;
        const bool val = (i < cnt);
        unsigned long long k = 0ULL;
        if (val) { k = cb[i]; keys[i] = k; }
        unsigned g = (unsigned)(k >> 32) >> 21;
        hist_wave_add(hist, g, val, lane);
    }
    __syncthreads();

    for (int lvl = 0; lvl < 3; ++lvl) {
        // suffix scan of 1024 pair-sums via wave shuffles
        int s = hist[2*tid] + hist[2*tid + 1];
        #pragma unroll
        for (int off = 1; off < 64; off <<= 1) {
            int t = __shfl_down(s, off);
            if (lane + off < 64) s += t;
        }
        if (lane == 0) wsuf[wv] = s;
        __syncthreads();
        if (tid < 16) {
            int t2 = wsuf[tid];
            #pragma unroll
            for (int off = 1; off < 16; off <<= 1) {
                int u = __shfl_down(t2, off);
                if (tid + off < 16) t2 += u;
            }
            wsuf[tid] = t2;
            if (tid == 0) wsuf[16] = 0;
        }
        __syncthreads();
        int ss = s + wsuf[wv + 1];
        ssLDS[tid] = ss;
        __syncthreads();

        const int need = sh_need;
        int sp  = ssLDS[tid];
        int spn = (tid < 1023) ? ssLDS[tid + 1] : 0;
        if (sp >= need && spn < need) sh_p = tid;
        __syncthreads();
        const int shift = (lvl == 0) ? 21 : ((lvl == 1) ? 10 : 0);
        if (tid == 0) {
            int p   = sh_p;
            int abv = (p < 1023) ? ssLDS[p + 1] : 0;
            int hi  = hist[2*p + 1];
            int g, above;
            if (abv + hi >= need) { g = 2*p + 1; above = abv; }
            else                  { g = 2*p;     above = abv + hi; }
            sh_need   = need - above;
            sh_prefix = sh_prefix | (g << shift);
        }
        __syncthreads();
        if (lvl == 2) break;

        // next-level histogram from LDS keys (wave-aggregated adds)
        hist[tid] = 0; hist[tid + 1024] = 0;
        __syncthreads();
        const unsigned nshift = (lvl == 0) ? 10u : 0u;
        const unsigned npmask = (lvl == 0) ? 0xFFE00000u : 0xFFFFFC00u;
        const unsigned prefix = (unsigned)sh_prefix;
        for (int i0 = 0; i0 < cnt; i0 += 1024) {
            const int i = i0 + tid;
            const bool val = (i < cnt);
            unsigned v = val ? (unsigned)(keys[i] >> 32) : 0u;
            bool pass = val && ((v & npmask) == prefix);
            unsigned g = (v >> nshift) & 0x7FF;
            hist_wave_add(hist, g, pass, lane);
        }
        __syncthreads();
    }

    // collect all keys with value >= T (exact 400th-largest value).
    const unsigned T = (unsigned)sh_prefix;
    const unsigned long long ltm = (1ULL << lane) - 1ULL;
    for (int i0 = 0; i0 < cnt; i0 += 1024) {
        const int i = i0 + tid;
        const bool val = (i < cnt);
        unsigned long long k = val ? keys[i] : 0ULL;
        bool pick = val && ((unsigned)(k >> 32) >= T);
        unsigned long long m = __ballot(pick);
        if (pick) {
            int lead = __ffsll(m) - 1;
            int basepos;
            if (lane == lead) basepos = atomicAdd(&sh_selcnt, (int)__popcll(m));
            basepos = __shfl(basepos, lead);
            int pos = basepos + (int)__popcll(m & ltm);
            if (pos < 1024) sel[pos] = k;
        }
    }
    __syncthreads();
    int sc = sh_selcnt; if (sc > 1024) sc = 1024;

    // counting rank (keys unique): rank = #{j: sel[j] > mine}
    unsigned long long mykey = (tid < sc) ? sel[tid] : 0ULL;
    int rank = 0;
    for (int j = 0; j < sc; ++j) rank += (sel[j] > mykey) ? 1 : 0;

    if (tid < sc && rank < K_) {
        unsigned vb  = (unsigned)(mykey >> 32);
        unsigned idx = ~((unsigned)mykey);
        int y = (int)(idx / W_), x = (int)(idx % W_);
        kpts[b*(K_*2) + rank*2 + 0] = (float)x + 0.5f;
        kpts[b*(K_*2) + rank*2 + 1] = (float)y + 0.5f;
        scores[b*K_ + rank] = __uint_as_float(vb);
    }
}

// ---------------------------------------------------------------------------
// bilinear descriptor sampling, one block per (channel, batch), 512 threads.
// kpts preloaded to registers before staging (latency overlap); whole 60x80
// plane staged in LDS (float4); writes UNNORMALIZED values.
__global__ __launch_bounds__(512) void sample_kernel(
    const float* __restrict__ desc, const float* __restrict__ kpts,
    float* __restrict__ sampled)
{
    const int c = blockIdx.x;   // 0..255
    const int b = blockIdx.y;   // 0..15
    const int tid = threadIdx.x;
    __shared__ float plane[HC_*WC_];   // 4800 floats = 19.2 KB

    // preload this thread's keypoint (clamped index; only tid<K_ writes out)
    const int kk = (tid < K_) ? tid : (K_-1);
    const float x = kpts[b*(K_*2) + 2*kk + 0];
    const float y = kpts[b*(K_*2) + 2*kk + 1];

    const float4* p4 = (const float4*)(desc + ((size_t)b*C_ + c) * (HC_*WC_));
    for (int i = tid; i < HC_*WC_/4; i += 512)
        ((float4*)plane)[i] = p4[i];
    __syncthreads();

    if (tid < K_) {
        float gx = (x - 3.5f) * (79.0f / 635.5f);
        float gy = (y - 3.5f) * (59.0f / 475.5f);
        float x0f = floorf(gx), y0f = floorf(gy);
        float wx = gx - x0f,   wy = gy - y0f;
        int x0 = min(max((int)x0f, 0), WC_-1);
        int x1 = min(x0 + 1, WC_-1);
        int y0 = min(max((int)y0f, 0), HC_-1);
        int y1 = min(y0 + 1, HC_-1);
        float d00 = plane[y0*WC_ + x0], d01 = plane[y0*WC_ + x1];
        float d10 = plane[y1*WC_ + x0], d11 = plane[y1*WC_ + x1];
        float v = d00*(1.0f-wx)*(1.0f-wy) + d01*wx*(1.0f-wy)
                + d10*(1.0f-wx)*wy        + d11*wx*wy;
        sampled[(size_t)b*(C_*K_) + c*K_ + tid] = v;
    }
}

// ---------------------------------------------------------------------------
// fused L2-normalize over channels, in place, values held in registers.
// grid (16, 25), block 256. Each block: 16 keypoints x 256 channels.
__global__ __launch_bounds__(256) void norm_fused(float* __restrict__ sampled)
{
    const int b  = blockIdx.x;
    const int k  = blockIdx.y * 16 + (threadIdx.x & 15);
    const int cs = threadIdx.x >> 4;          // 0..15
    const int lane = threadIdx.x & 63;
    const int wv   = threadIdx.x >> 6;
    float* base = sampled + (size_t)b*(C_*K_);

    float v[16];
    float acc = 0.0f;
    #pragma unroll
    for (int i = 0; i < 16; ++i) {
        int c = cs + 16*i;
        float t = base[c*K_ + k];
        v[i] = t;
        acc += t*t;
    }
    acc += __shfl_xor(acc, 16);
    acc += __shfl_xor(acc, 32);
    __shared__ float wpart[4][16];
    if (lane < 16) wpart[wv][lane] = acc;
    __syncthreads();
    const int kk = threadIdx.x & 15;
    float s = wpart[0][kk] + wpart[1][kk] + wpart[2][kk] + wpart[3][kk];
    float inv = rsqrtf(s + 1e-12f);
    #pragma unroll
    for (int i = 0; i < 16; ++i) {
        int c = cs + 16*i;
        base[c*K_ + k] = v[i] * inv;
    }
}

// ---------------------------------------------------------------------------
extern "C" void kernel_launch(void* const* d_in, const int* in_sizes, int n_in,
                              void* d_out, int out_size, void* d_ws, size_t ws_size,
                              hipStream_t stream) {
    const float* heat = (const float*)d_in[0];   // (16,1,480,640)
    const float* desc = (const float*)d_in[1];   // (16,256,60,80)
    float* out      = (float*)d_out;
    float* kpts     = out + OFF_KPTS;
    float* scores   = out + OFF_SCORES;
    float* sampled  = out + OFF_SAMPLED;
    float* out_heat = out + OFF_HEAT;

    unsigned* count = (unsigned*)d_ws;            // 16 counters, poison-based
    unsigned long long* cand =
        (unsigned long long*)((char*)d_ws + 16*COUNT_STRIDE*sizeof(unsigned)); // 1 MB

    nms_kernel<<<dim3(W_/TW, H_/TH, B_), dim3(64, 4), 0, stream>>>(
        heat, out_heat, cand, count);
    topk_kernel<<<B_, 1024, 0, stream>>>(cand, count, kpts, scores);
    sample_kernel<<<dim3(C_, B_), 512, 0, stream>>>(desc, kpts, sampled);
    norm_fused<<<dim3(B_, 25), 256, 0, stream>>>(sampled);
}